// Round 3
// baseline (326.441 us; speedup 1.0000x reference)
//
#include <hip/hip_runtime.h>

// GCN_4492535792198: 3-layer GCN forward on MI355X (gfx950).
// N=50000, E=800000, D: 128->128->64. Outputs: logp[N,64], e1[N,128], e2[N,128], e3[N,64].
// R3: 12 launches (was 17), agg unroll 8, bf16 hidden-state feed-forward, agg3+log_softmax fused.

typedef __attribute__((ext_vector_type(8))) short short8;   // 8 x bf16 (4 VGPRs)
typedef __attribute__((ext_vector_type(4))) float f32x4;

__device__ __forceinline__ ushort f2bf(float f) {
    union { float f; unsigned u; } a; a.f = f;
    unsigned r = a.u + 0x7fffu + ((a.u >> 16) & 1u);   // RNE (finite data)
    return (ushort)(r >> 16);
}
__device__ __forceinline__ float bflo(unsigned u) { return __uint_as_float(u << 16); }
__device__ __forceinline__ float bfhi(unsigned u) { return __uint_as_float(u & 0xffff0000u); }

__device__ __forceinline__ int edge_at(const void* ei, int is64, long long i) {
    if (is64) return (int)((const long long*)ei)[i];
    return ((const int*)ei)[i];
}

// ---------------- prep: dtype detect + weight transpose/bf16 + zero counters ----------------
// block 0: detect; blocks 1..160: wprep (40960 elems); blocks 161..: zero cnt/fillc.
__global__ __launch_bounds__(256) void prep_kernel(
    const void* ei, int* __restrict__ flag,
    const float* __restrict__ W1, const float* __restrict__ W2, const float* __restrict__ W3,
    ushort* __restrict__ Wt1, ushort* __restrict__ Wt2, ushort* __restrict__ Wt3,
    int* __restrict__ cnt, int* __restrict__ fillc, int n) {
    const int b = blockIdx.x, tid = threadIdx.x;
    if (b == 0) {
        if (tid < 64) {
            long long v = ((const long long*)ei)[tid];
            int bad = (v < 0 || v >= (1LL << 32)) ? 1 : 0;
            unsigned long long m = __ballot(bad);
            if (tid == 0) *flag = (m == 0ULL) ? 1 : 0;   // 1 => int64
        }
    } else if (b <= 160) {
        int i = (b - 1) * 256 + tid;
        if (i < 16384) {
            int nn = i >> 7, k = i & 127;
            Wt1[i] = f2bf(W1[k * 128 + nn]);
        } else if (i < 32768) {
            int j = i - 16384; int nn = j >> 7, k = j & 127;
            Wt2[j] = f2bf(W2[k * 128 + nn]);
        } else if (i < 40960) {
            int j = i - 32768; int nn = j >> 7, k = j & 127;
            Wt3[j] = f2bf(W3[k * 64 + nn]);
        }
    } else {
        int i = (b - 161) * 256 + tid;
        if (i < n) { cnt[i] = 0; fillc[i] = 0; }
    }
}

__global__ void hist_kernel(const void* ei, const int* __restrict__ flag,
                            int* __restrict__ cnt, int E) {
    int e = blockIdx.x * blockDim.x + threadIdx.x;
    if (e >= E) return;
    int is64 = flag[0];
    int d = edge_at(ei, is64, (long long)E + e);
    atomicAdd(&cnt[d], 1);
}

// block-level exclusive scan + dinv computation
__global__ void scan1_kernel(const int* __restrict__ cnt, int* __restrict__ rowptr,
                             int* __restrict__ bsum, float* __restrict__ dinv, int n) {
    int tid = threadIdx.x;
    int gid = blockIdx.x * 1024 + tid;
    int v = (gid < n) ? cnt[gid] : 0;
    if (gid < n) dinv[gid] = rsqrtf((float)(v + 1));    // +1 self loop
    int lane = tid & 63, wid = tid >> 6;
    int x = v;
#pragma unroll
    for (int off = 1; off < 64; off <<= 1) {
        int t = __shfl_up(x, off, 64);
        if (lane >= off) x += t;
    }
    __shared__ int wsum[16];
    if (lane == 63) wsum[wid] = x;
    __syncthreads();
    if (tid < 64) {
        int y = (lane < 16) ? wsum[lane] : 0;
#pragma unroll
        for (int off = 1; off < 16; off <<= 1) {
            int t = __shfl_up(y, off, 64);
            if (lane >= off) y += t;
        }
        if (lane < 16) wsum[lane] = y;
    }
    __syncthreads();
    int woff = (wid > 0) ? wsum[wid - 1] : 0;
    int incl = x + woff;
    if (gid < n) rowptr[gid] = incl - v;
    if (tid == 1023) bsum[blockIdx.x] = incl;
}

__global__ void scan2_kernel(const int* __restrict__ bsum, int* __restrict__ boff,
                             int nb, int* __restrict__ rowptr, int n, int E) {
    int lane = threadIdx.x;   // 64 threads
    int carry = 0;
    for (int base = 0; base < nb; base += 64) {
        int idx = base + lane;
        int v = (idx < nb) ? bsum[idx] : 0;
        int x = v;
#pragma unroll
        for (int off = 1; off < 64; off <<= 1) {
            int t = __shfl_up(x, off, 64);
            if (lane >= off) x += t;
        }
        if (idx < nb) boff[idx] = carry + x - v;
        carry += __shfl(x, 63, 64);
    }
    if (lane == 0) rowptr[n] = E;
}

__global__ void scan3_kernel(int* __restrict__ rowptr, const int* __restrict__ boff, int n) {
    int i = blockIdx.x * blockDim.x + threadIdx.x;
    if (i < n) rowptr[i] += boff[i >> 10];
}

__global__ void fill_kernel(const void* ei, const int* __restrict__ flag,
                            const int* __restrict__ rowptr, int* __restrict__ fillc,
                            int* __restrict__ col, int E) {
    int e = blockIdx.x * blockDim.x + threadIdx.x;
    if (e >= E) return;
    int is64 = flag[0];
    int s = edge_at(ei, is64, e);
    int d = edge_at(ei, is64, (long long)E + e);
    int p = rowptr[d] + atomicAdd(&fillc[d], 1);
    col[p] = s;
}

// ---------------- MFMA GEMM: xw[M,DOUT](bf16) = A[M,128] @ W ----------------
// 128-row x DOUT tile per 256-thread block. LDS stride 136 bf16: 2-way (free) bank aliasing.
// BF16IN: A is bf16[M,128] (already activated); else fp32.
template <int DOUT, bool BF16IN>
__global__ __launch_bounds__(256) void mfma_gemm_kernel(
    const void* __restrict__ Ain, const ushort* __restrict__ Wt,
    ushort* __restrict__ xw, int M) {
    constexpr int NT = DOUT / 16;
    __shared__ ushort As[128 * 136];
    __shared__ ushort Ws[DOUT * 136];
    const int tid = threadIdx.x;
    const int r0 = blockIdx.x * 128;
    const int wid = tid >> 6;
    const int lane = tid & 63;
    const int m = lane & 15, quad = lane >> 4;

    if (BF16IN) {
        const uint4* A4 = (const uint4*)Ain;      // row pitch 16 uint4
#pragma unroll
        for (int i = 0; i < 8; ++i) {
            int li = tid + i * 256;               // 0..2047 chunk16 slots
            int row = li >> 4, c = li & 15;
            uint4 v = make_uint4(0u, 0u, 0u, 0u);
            int gr = r0 + row;
            if (gr < M) v = A4[(size_t)gr * 16 + c];
            *(uint4*)&As[row * 136 + c * 8] = v;
        }
    } else {
        const float* A = (const float*)Ain;
#pragma unroll
        for (int i = 0; i < 16; ++i) {
            int li = tid + i * 256;               // 0..4095 float4 slots
            int row = li >> 5, c4 = li & 31;
            float4 v = make_float4(0.f, 0.f, 0.f, 0.f);
            int gr = r0 + row;
            if (gr < M) v = ((const float4*)(A + (size_t)gr * 128))[c4];
            ushort4 u;
            u.x = f2bf(v.x); u.y = f2bf(v.y); u.z = f2bf(v.z); u.w = f2bf(v.w);
            *(ushort4*)&As[row * 136 + c4 * 4] = u;
        }
    }
#pragma unroll
    for (int i = 0; i < DOUT / 16; ++i) {
        int li = tid + i * 256;
        int nn = li >> 4, c = li & 15;
        uint4 v = ((const uint4*)Wt)[li];
        *(uint4*)&Ws[nn * 136 + c * 8] = v;
    }
    __syncthreads();

    f32x4 acc[2][NT];
#pragma unroll
    for (int rt = 0; rt < 2; ++rt)
#pragma unroll
        for (int nt = 0; nt < NT; ++nt) acc[rt][nt] = (f32x4){0.f, 0.f, 0.f, 0.f};

#pragma unroll
    for (int kt = 0; kt < 4; ++kt) {
        const int ko = kt * 32 + quad * 8;
        short8 af0 = *(const short8*)&As[(wid * 32 + m) * 136 + ko];
        short8 af1 = *(const short8*)&As[(wid * 32 + 16 + m) * 136 + ko];
        short8 bf_[NT];
#pragma unroll
        for (int nt = 0; nt < NT; ++nt)
            bf_[nt] = *(const short8*)&Ws[(nt * 16 + m) * 136 + ko];
#pragma unroll
        for (int nt = 0; nt < NT; ++nt) {
            acc[0][nt] = __builtin_amdgcn_mfma_f32_16x16x32_bf16(af0, bf_[nt], acc[0][nt], 0, 0, 0);
            acc[1][nt] = __builtin_amdgcn_mfma_f32_16x16x32_bf16(af1, bf_[nt], acc[1][nt], 0, 0, 0);
        }
    }
    // C layout: col=lane&15, row=quad*4+i
#pragma unroll
    for (int rt = 0; rt < 2; ++rt)
#pragma unroll
        for (int nt = 0; nt < NT; ++nt)
#pragma unroll
            for (int i = 0; i < 4; ++i) {
                int row = r0 + wid * 32 + rt * 16 + quad * 4 + i;
                if (row < M) xw[(size_t)row * DOUT + nt * 16 + m] = f2bf(acc[rt][nt][i]);
            }
}

// ---------------- aggregation: out = di*sum(dinv[s]*xw[s]) + di^2*xw[i] + b ----------------
// TPN lanes/node, 16B bf16 per lane (D = TPN*8). RELU_OUT: also emit hb=bf16(relu(out)).
// LSM: fuse 64-class log_softmax (TPN==8 only), emit logp.
template <int TPN, bool RELU_OUT, bool LSM>
__global__ __launch_bounds__(256) void agg_kernel(
    const ushort* __restrict__ xw, const float* __restrict__ dinv,
    const int* __restrict__ rowptr, const int* __restrict__ col,
    const float* __restrict__ bias, float* __restrict__ out,
    ushort* __restrict__ hb, float* __restrict__ logp, int n) {
    const int tid = threadIdx.x;
    const int gpb = 256 / TPN;
    const int node = blockIdx.x * gpb + tid / TPN;
    const int j = tid % TPN;
    if (node >= n) return;
    const uint4* xw4 = (const uint4*)xw;   // row pitch = TPN uint4
    const float di = dinv[node];
    const int p0 = rowptr[node], p1 = rowptr[node + 1];
    float acc[8];
#pragma unroll
    for (int i = 0; i < 8; ++i) acc[i] = 0.f;

    int p = p0;
    for (; p + 8 <= p1; p += 8) {           // 8 gathers in flight
        int s[8]; float w[8]; uint4 v[8];
#pragma unroll
        for (int q = 0; q < 8; ++q) s[q] = col[p + q];
#pragma unroll
        for (int q = 0; q < 8; ++q) w[q] = dinv[s[q]];
#pragma unroll
        for (int q = 0; q < 8; ++q) v[q] = xw4[(size_t)s[q] * TPN + j];
#pragma unroll
        for (int q = 0; q < 8; ++q) {
            acc[0] += w[q] * bflo(v[q].x); acc[1] += w[q] * bfhi(v[q].x);
            acc[2] += w[q] * bflo(v[q].y); acc[3] += w[q] * bfhi(v[q].y);
            acc[4] += w[q] * bflo(v[q].z); acc[5] += w[q] * bfhi(v[q].z);
            acc[6] += w[q] * bflo(v[q].w); acc[7] += w[q] * bfhi(v[q].w);
        }
    }
    for (; p < p1; ++p) {
        int s = col[p];
        float w = dinv[s];
        uint4 v = xw4[(size_t)s * TPN + j];
        acc[0] += w * bflo(v.x); acc[1] += w * bfhi(v.x);
        acc[2] += w * bflo(v.y); acc[3] += w * bfhi(v.y);
        acc[4] += w * bflo(v.z); acc[5] += w * bfhi(v.z);
        acc[6] += w * bflo(v.w); acc[7] += w * bfhi(v.w);
    }
    uint4 vs = xw4[(size_t)node * TPN + j];
    const float self[8] = { bflo(vs.x), bfhi(vs.x), bflo(vs.y), bfhi(vs.y),
                            bflo(vs.z), bfhi(vs.z), bflo(vs.w), bfhi(vs.w) };
    const float4 blo = ((const float4*)bias)[2 * j];
    const float4 bhi = ((const float4*)bias)[2 * j + 1];
    const float bb[8] = { blo.x, blo.y, blo.z, blo.w, bhi.x, bhi.y, bhi.z, bhi.w };
    const float dii = di * di;
    float o[8];
#pragma unroll
    for (int i = 0; i < 8; ++i) o[i] = di * acc[i] + dii * self[i] + bb[i];

    float* op = out + (size_t)node * (TPN * 8) + j * 8;
    ((float4*)op)[0] = make_float4(o[0], o[1], o[2], o[3]);
    ((float4*)op)[1] = make_float4(o[4], o[5], o[6], o[7]);

    if (RELU_OUT) {
        uint4 h;
        h.x = (unsigned)f2bf(fmaxf(o[0], 0.f)) | ((unsigned)f2bf(fmaxf(o[1], 0.f)) << 16);
        h.y = (unsigned)f2bf(fmaxf(o[2], 0.f)) | ((unsigned)f2bf(fmaxf(o[3], 0.f)) << 16);
        h.z = (unsigned)f2bf(fmaxf(o[4], 0.f)) | ((unsigned)f2bf(fmaxf(o[5], 0.f)) << 16);
        h.w = (unsigned)f2bf(fmaxf(o[6], 0.f)) | ((unsigned)f2bf(fmaxf(o[7], 0.f)) << 16);
        ((uint4*)hb)[(size_t)node * TPN + j] = h;
    }
    if (LSM) {
        // 8 lanes per node (aligned), 64 classes; reduce max & sum-exp across lanes 1,2,4
        float mx = o[0];
#pragma unroll
        for (int i = 1; i < 8; ++i) mx = fmaxf(mx, o[i]);
#pragma unroll
        for (int msk = 1; msk < 8; msk <<= 1) mx = fmaxf(mx, __shfl_xor(mx, msk, 64));
        float sm = 0.f;
#pragma unroll
        for (int i = 0; i < 8; ++i) sm += __expf(o[i] - mx);
#pragma unroll
        for (int msk = 1; msk < 8; msk <<= 1) sm += __shfl_xor(sm, msk, 64);
        const float lse = mx + __logf(sm);
        float* lp = logp + (size_t)node * 64 + j * 8;
        ((float4*)lp)[0] = make_float4(o[0] - lse, o[1] - lse, o[2] - lse, o[3] - lse);
        ((float4*)lp)[1] = make_float4(o[4] - lse, o[5] - lse, o[6] - lse, o[7] - lse);
    }
}

// ---------------- driver ----------------
extern "C" void kernel_launch(void* const* d_in, const int* in_sizes, int n_in,
                              void* d_out, int out_size, void* d_ws, size_t ws_size,
                              hipStream_t stream) {
    const float* x  = (const float*)d_in[0];
    const void*  ei = d_in[1];
    const float* W1 = (const float*)d_in[2];
    const float* b1 = (const float*)d_in[3];
    const float* W2 = (const float*)d_in[4];
    const float* b2 = (const float*)d_in[5];
    const float* W3 = (const float*)d_in[6];
    const float* b3 = (const float*)d_in[7];
    float* out = (float*)d_out;

    const int N = in_sizes[0] / 128;   // 50000
    const int E = in_sizes[1] / 2;     // 800000

    char* w = (char*)d_ws;
    size_t off = 0;
    auto alloc = [&](size_t bytes) -> void* {
        void* p = w + off;
        off = (off + bytes + 255) & ~(size_t)255;
        return p;
    };
    int*    flag   = (int*)alloc(4);
    int*    cnt    = (int*)alloc((size_t)N * 4);
    int*    fillc  = (int*)alloc((size_t)N * 4);
    int*    rowptr = (int*)alloc((size_t)(N + 1) * 4);
    int*    bsum   = (int*)alloc(4096);
    int*    boff   = (int*)alloc(4096);
    float*  dinv   = (float*)alloc((size_t)N * 4);
    int*    col    = (int*)alloc((size_t)E * 4);
    ushort* xw     = (ushort*)alloc((size_t)N * 128 * 2);   // bf16 A@W
    ushort* hb     = (ushort*)alloc((size_t)N * 128 * 2);   // bf16 relu(e)
    ushort* Wt1    = (ushort*)alloc(16384 * 2);
    ushort* Wt2    = (ushort*)alloc(16384 * 2);
    ushort* Wt3    = (ushort*)alloc(8192 * 2);

    float* logp = out;
    float* e1 = out + (size_t)N * 64;
    float* e2 = e1 + (size_t)N * 128;
    float* e3 = e2 + (size_t)N * 128;

    const int nb = (N + 1023) / 1024;
    const int zb = (N + 255) / 256;

    prep_kernel<<<161 + zb, 256, 0, stream>>>(ei, flag, W1, W2, W3, Wt1, Wt2, Wt3,
                                              cnt, fillc, N);
    hist_kernel<<<(E + 255) / 256, 256, 0, stream>>>(ei, flag, cnt, E);
    scan1_kernel<<<nb, 1024, 0, stream>>>(cnt, rowptr, bsum, dinv, N);
    scan2_kernel<<<1, 64, 0, stream>>>(bsum, boff, nb, rowptr, N, E);
    scan3_kernel<<<zb, 256, 0, stream>>>(rowptr, boff, N);
    fill_kernel<<<(E + 255) / 256, 256, 0, stream>>>(ei, flag, rowptr, fillc, col, E);

    const int gblocks = (N + 127) / 128;
    // layer 1 (fp32 input, no activation)
    mfma_gemm_kernel<128, false><<<gblocks, 256, 0, stream>>>(x, Wt1, xw, N);
    agg_kernel<16, true, false><<<(N + 15) / 16, 256, 0, stream>>>(
        xw, dinv, rowptr, col, b1, e1, hb, nullptr, N);
    // layer 2 (bf16 relu'd input)
    mfma_gemm_kernel<128, true><<<gblocks, 256, 0, stream>>>(hb, Wt2, xw, N);
    agg_kernel<16, true, false><<<(N + 15) / 16, 256, 0, stream>>>(
        xw, dinv, rowptr, col, b2, e2, hb, nullptr, N);
    // layer 3 (bf16, Dout=64) + fused log_softmax
    mfma_gemm_kernel<64, true><<<gblocks, 256, 0, stream>>>(hb, Wt3, xw, N);
    agg_kernel<8, false, true><<<(N + 31) / 32, 256, 0, stream>>>(
        xw, dinv, rowptr, col, b3, e3, nullptr, logp, N);
}